// Round 6
// baseline (271.658 us; speedup 1.0000x reference)
//
#include <hip/hip_runtime.h>
#include <math.h>

#define HH 384
#define WW 384
#define TX 6                 // 6x6 tiles of 64x64 per 384x384 image
#define NTILES 9792          // 6*6*272
#define IMG_STRIDE (HH * WW)
#define LDS_STRIDE 76        // floats per staged row (72 data + 4 pad, 16B-aligned rows)
#define ROWS 66
#define BUFSZ (ROWS * LDS_STRIDE)   // 5016 floats = 20064 B per buffer
#define NSEG 1188            // 66 rows * 18 float4 segments
#define GRID 1024            // exactly 4 blocks/CU resident (2x20 KB LDS)

typedef float f4_t __attribute__((ext_vector_type(4)));

__device__ __forceinline__ float max3f(float a, float b, float c) {
    return fmaxf(fmaxf(a, b), c);   // -> v_max3_f32
}
__device__ __forceinline__ float fast_sigmoid(float v) {
    return __fdividef(1.0f, 1.0f + __expf(-v));
}

// Issue 5 independent float4 loads for one 66x72 halo tile. No waits here:
// results are consumed by write_lds() AFTER the compute phase, so the loads
// stay in flight while the previous tile is processed.
__device__ __forceinline__ void issue_loads(const float* __restrict__ in,
                                            int tile, int tid,
                                            f4_t reg[5], bool vld[5]) {
    int tx  = tile % TX;
    int t2  = tile / TX;
    int ty  = t2 % TX;
    int img = t2 / TX;
    const float* ib = in + (size_t)img * IMG_STRIDE;
    int x0 = tx * 64, y0 = ty * 64;
#pragma unroll
    for (int k = 0; k < 5; ++k) {
        int e   = tid + k * 256;
        int row = e / 18;
        int c4  = e - row * 18;
        int gy  = y0 - 1 + row;
        int gx  = x0 - 4 + c4 * 4;       // float4-aligned (x0 % 64 == 0)
        bool v  = (e < NSEG) & ((unsigned)gy < (unsigned)HH)
                             & ((unsigned)gx <= (unsigned)(WW - 4));
        int cy = v ? gy : 0;
        int cx = v ? gx : 0;
        reg[k] = *(const f4_t*)(ib + (size_t)cy * WW + cx);  // clamped, safe
        vld[k] = v;
    }
}

__device__ __forceinline__ void write_lds(float* __restrict__ B, int tid,
                                          const f4_t reg[5], const bool vld[5]) {
    const float NEG = -INFINITY;
    f4_t NEG4 = {NEG, NEG, NEG, NEG};
#pragma unroll
    for (int k = 0; k < 5; ++k) {
        int e = tid + k * 256;
        if (e < NSEG) {
            int row = e / 18;
            int c4  = e - row * 18;
            *(f4_t*)(B + row * LDS_STRIDE + c4 * 4) = vld[k] ? reg[k] : NEG4;
        }
    }
}

__device__ __forceinline__ void compute_tile(const float* __restrict__ A,
                                             int tile, int tid,
                                             float* __restrict__ out) {
    int tx  = tile % TX;
    int t2  = tile / TX;
    int ty  = t2 % TX;
    int img = t2 / TX;
    int x0 = tx * 64, y0 = ty * 64;

    int ctx = tid & 15;      // 16 x-groups of 4 px
    int cty = tid >> 4;      // 16 y-groups of 4 rows
    int rb  = cty * 4;
    int cb  = ctx * 4;

    // staged col s <-> gx = x0-4+s; output col x0+cb+i needs s = cb+3+i..cb+5+i
    const float* Sp = A + rb * LDS_STRIDE + cb + 3;
    float vals[6][6];
#pragma unroll
    for (int r = 0; r < 6; ++r)
#pragma unroll
        for (int c = 0; c < 6; ++c)
            vals[c][r] = Sp[r * LDS_STRIDE + c];

    float vm[6][4];
#pragma unroll
    for (int c = 0; c < 6; ++c)
#pragma unroll
        for (int r = 0; r < 4; ++r)
            vm[c][r] = max3f(vals[c][r], vals[c][r + 1], vals[c][r + 2]);

    float* ob = out + (size_t)img * IMG_STRIDE
                    + (size_t)(y0 + rb) * WW + x0 + cb;
#pragma unroll
    for (int r = 0; r < 4; ++r) {
        f4_t o;
        float p, m, v;
        m = max3f(vm[0][r], vm[1][r], vm[2][r]); v = vals[1][r + 1];
        p = fast_sigmoid(v); o.x = (m == v && p > 0.05f) ? p : 0.0f;
        m = max3f(vm[1][r], vm[2][r], vm[3][r]); v = vals[2][r + 1];
        p = fast_sigmoid(v); o.y = (m == v && p > 0.05f) ? p : 0.0f;
        m = max3f(vm[2][r], vm[3][r], vm[4][r]); v = vals[3][r + 1];
        p = fast_sigmoid(v); o.z = (m == v && p > 0.05f) ? p : 0.0f;
        m = max3f(vm[3][r], vm[4][r], vm[5][r]); v = vals[4][r + 1];
        p = fast_sigmoid(v); o.w = (m == v && p > 0.05f) ? p : 0.0f;
        __builtin_nontemporal_store(o, (f4_t*)(ob + (size_t)r * WW));
    }
}

__global__ __launch_bounds__(256) void
heatmap_peaks_kernel(const float* __restrict__ in, float* __restrict__ out) {
    __shared__ float S[2 * BUFSZ];
    int tid = threadIdx.x;

    int t = blockIdx.x;
    f4_t reg[5]; bool vld[5];

    // prologue: stage first tile
    issue_loads(in, t, tid, reg, vld);
    write_lds(S, tid, reg, vld);
    __syncthreads();

    int buf = 0;
    while (t < NTILES) {
        int tn = t + GRID;
        bool more = (tn < NTILES);           // uniform within block
        if (more) issue_loads(in, tn, tid, reg, vld);   // loads fly during compute
        compute_tile(S + buf * BUFSZ, t, tid, out);
        if (more) write_lds(S + (buf ^ 1) * BUFSZ, tid, reg, vld); // vmcnt wait here
        __syncthreads();                     // drain is cheap: all consumed
        buf ^= 1;
        t = tn;
    }
}

extern "C" void kernel_launch(void* const* d_in, const int* in_sizes, int n_in,
                              void* d_out, int out_size, void* d_ws, size_t ws_size,
                              hipStream_t stream) {
    const float* in = (const float*)d_in[0];
    float* out = (float*)d_out;
    heatmap_peaks_kernel<<<GRID, 256, 0, stream>>>(in, out);
}

// Round 7
// 268.507 us; speedup vs baseline: 1.0117x; 1.0117x over previous
//
#include <hip/hip_runtime.h>
#include <math.h>

#define HH 384
#define WW 384
#define XQ 96            // WW/4 column segments
#define YQ 96            // HH/4 row quads
#define NIMG 272         // 16*17
#define IMG_STRIDE (HH * WW)
#define TOTAL (NIMG * YQ * XQ)   // 2,506,752 threads = 9792 * 256

typedef float f4_t __attribute__((ext_vector_type(4)));

__device__ __forceinline__ float max3f(float a, float b, float c) {
    return fmaxf(fmaxf(a, b), c);   // -> v_max3_f32
}
__device__ __forceinline__ float fast_sigmoid(float v) {
    return __fdividef(1.0f, 1.0f + __expf(-v));
}

__global__ __launch_bounds__(256, 4) void
heatmap_peaks_kernel(const float* __restrict__ in, float* __restrict__ out) {
    int vi   = blockIdx.x * 256 + threadIdx.x;
    int lane = threadIdx.x & 63;

    int x4   = vi % XQ;
    int rest = vi / XQ;
    int yq   = rest % YQ;
    int img  = rest / YQ;
    int x0 = x4 * 4, y0 = yq * 4;

    const float* base = in + (size_t)img * IMG_STRIDE + x0;
    const float NEG = -INFINITY;

    // ---- 6 independent float4 row loads (rows y0-1 .. y0+4), clamped addr.
    // All issued before any consumption: one vmcnt drain, max MLP. ----
    f4_t R[6];
    bool rv[6];
#pragma unroll
    for (int j = 0; j < 6; ++j) {
        int gy = y0 - 1 + j;
        bool v = (unsigned)gy < (unsigned)HH;
        int cy = v ? gy : 0;
        R[j] = *(const f4_t*)(base + (size_t)cy * WW);
        rv[j] = v;
    }

    // ---- masked edge-column loads: only lane 0 / lane 63 of each wave
    // (at non-image-edge) touch memory; issued alongside the row loads ----
    bool doL = (x4 > 0) && (lane == 0);
    bool doR = (x4 < XQ - 1) && (lane == 63);
    float el[6], er[6];
#pragma unroll
    for (int j = 0; j < 6; ++j) {
        int gy = y0 - 1 + j;
        bool v = (unsigned)gy < (unsigned)HH;
        int cy = v ? gy : 0;
        el[j] = (doL && v) ? base[(size_t)cy * WW - 1] : NEG;
        er[j] = (doR && v) ? base[(size_t)cy * WW + 4] : NEG;
    }

    f4_t NEG4 = {NEG, NEG, NEG, NEG};
#pragma unroll
    for (int j = 0; j < 6; ++j)
        if (!rv[j]) R[j] = NEG4;

    // ---- vertical 3-max per column, 4 output rows ----
    f4_t vm[4];
#pragma unroll
    for (int r = 0; r < 4; ++r) {
        vm[r].x = max3f(R[r].x, R[r+1].x, R[r+2].x);
        vm[r].y = max3f(R[r].y, R[r+1].y, R[r+2].y);
        vm[r].z = max3f(R[r].z, R[r+1].z, R[r+2].z);
        vm[r].w = max3f(R[r].w, R[r+1].w, R[r+2].w);
    }

    float* ob = out + (size_t)img * IMG_STRIDE + (size_t)y0 * WW + x0;

#pragma unroll
    for (int r = 0; r < 4; ++r) {
        // horizontal halos of the column-max via cross-lane shuffle;
        // wave-wrap / image-edge cases are overwritten below
        float lv = __shfl_up(vm[r].w, 1);
        float rw = __shfl_down(vm[r].x, 1);
        if (x4 == 0)            lv = NEG;
        else if (lane == 0)     lv = max3f(el[r], el[r+1], el[r+2]);
        if (x4 == XQ - 1)       rw = NEG;
        else if (lane == 63)    rw = max3f(er[r], er[r+1], er[r+2]);

        f4_t m;
        m.x = max3f(lv,       vm[r].x, vm[r].y);
        m.y = max3f(vm[r].x,  vm[r].y, vm[r].z);
        m.z = max3f(vm[r].y,  vm[r].z, vm[r].w);
        m.w = max3f(vm[r].z,  vm[r].w, rw);

        f4_t c = R[r + 1];
        f4_t o;
        float p;
        p = fast_sigmoid(c.x); o.x = (m.x == c.x && p > 0.05f) ? p : 0.0f;
        p = fast_sigmoid(c.y); o.y = (m.y == c.y && p > 0.05f) ? p : 0.0f;
        p = fast_sigmoid(c.z); o.z = (m.z == c.z && p > 0.05f) ? p : 0.0f;
        p = fast_sigmoid(c.w); o.w = (m.w == c.w && p > 0.05f) ? p : 0.0f;

        // output never re-read: keep L2/L3 for the input stream; no barrier
        // ever follows, so NT store acks drain only at wave end.
        __builtin_nontemporal_store(o, (f4_t*)(ob + (size_t)r * WW));
    }
}

extern "C" void kernel_launch(void* const* d_in, const int* in_sizes, int n_in,
                              void* d_out, int out_size, void* d_ws, size_t ws_size,
                              hipStream_t stream) {
    const float* in = (const float*)d_in[0];
    float* out = (float*)d_out;
    int blocks = TOTAL / 256;   // 9792
    heatmap_peaks_kernel<<<blocks, 256, 0, stream>>>(in, out);
}